// Round 2
// baseline (512.749 us; speedup 1.0000x reference)
//
#include <hip/hip_runtime.h>
#include <hip/hip_bf16.h>

// B=8, E=64, CIN=C=PRE=128, DME=DEN=32, edge types 10, path types 20.
// All float tensors are fp32 on device (per reference); ints are int32.
// Internal: fp32 compute; ws holds fp32 small intermediates + bf16 xret/yret/h
// (bf16 there only to halve footprint; error ~4e-3 << 8.9e-2 threshold).

typedef unsigned short u16;
typedef unsigned int u32;

#define NB 8
#define NE 64
#define NC 128

__device__ __forceinline__ float b2f(u16 u) { return __uint_as_float(((u32)u) << 16); }
__device__ __forceinline__ u16 f2b(float f) {
    u32 x = __float_as_uint(f);
    u32 r = (x + 0x7fffu + ((x >> 16) & 1u)) >> 16;   // RNE
    return (u16)r;
}
__device__ __forceinline__ float lk(float v) { return v >= 0.f ? v : 0.1f * v; }

// ---------------- K0: transpose conv1_w -> wT1[c1][o], conv2_w -> wT2[c*9+k][o]
__global__ __launch_bounds__(256) void k_prep(const float* __restrict__ w1, const float* __restrict__ w2,
                                              float* __restrict__ wT1, float* __restrict__ wT2) {
    int idx = blockIdx.x * 256 + threadIdx.x;
    if (idx < 384 * 128) {
        int o = idx & 127, c1 = idx >> 7;
        wT1[idx] = w1[o * 384 + c1];
    }
    int idx2 = idx - 384 * 128;
    if (idx2 >= 0 && idx2 < 1152 * 128) {
        int o = idx2 & 127, ck = idx2 >> 7;
        wT2[idx2] = w2[o * 1152 + ck];
    }
}

// ---------------- K1: x_f[b,c,m] = sum_i xc1_w[c,i] x[b,i,m]  (and y_f)
__global__ __launch_bounds__(64) void k_feat(const float* __restrict__ x, const float* __restrict__ y,
                                             const float* __restrict__ xc1, const float* __restrict__ yc1,
                                             float* __restrict__ xf, float* __restrict__ yf) {
    int blk = blockIdx.x;
    int which = blk >> 10; int r = blk & 1023;
    int b = r >> 7, c = r & 127;
    const float* in = which ? y : x;
    const float* w = which ? yc1 : xc1;
    float* out = which ? yf : xf;
    int m = threadIdx.x;
    const float* wr = w + c * NC;
    const float* ib = in + b * NC * NE + m;
    float acc = 0.f;
#pragma unroll 8
    for (int i = 0; i < NC; ++i) acc += wr[i] * ib[i * NE];
    out[(b * NC + c) * NE + m] = acc;
}

// ---------------- K1L: x_lin[b,m,i] = sum_j xlin_w[i,j] x[b,j,m]  (stored [b][ent][i])
__global__ __launch_bounds__(128) void k_lin(const float* __restrict__ x, const float* __restrict__ y,
                                             const float* __restrict__ xlw, const float* __restrict__ ylw,
                                             float* __restrict__ xl, float* __restrict__ yl) {
    int blk = blockIdx.x;
    int which = blk >> 9; int r = blk & 511;
    int b = r >> 6, ent = r & 63;
    const float* in = which ? y : x;
    const float* w = which ? ylw : xlw;
    float* out = which ? yl : xl;
    int i = threadIdx.x;
    float acc = 0.f;
#pragma unroll 4
    for (int j = 0; j < NC; ++j) acc += w[i * NC + j] * in[(b * NC + j) * NE + ent];
    out[(b * NE + ent) * NC + i] = acc;
}

// ---------------- K1b: x_self, y_other, L=leaky(xs[j]+yo[i]), gbase = L + edge + m_bias
__global__ __launch_bounds__(64) void k_selfother(const float* __restrict__ xf, const float* __restrict__ yf,
                                                  const float* __restrict__ xc2w, const float* __restrict__ xc2b,
                                                  const float* __restrict__ yc2w, const float* __restrict__ yc2b,
                                                  const float* __restrict__ etab, const float* __restrict__ econv,
                                                  const int* __restrict__ edge_mat, const float* __restrict__ m_bias,
                                                  float* __restrict__ Lw, float* __restrict__ gb) {
    int b = blockIdx.x; int t = threadIdx.x;
    __shared__ float sXs[64], sYo[64], sEd[16];
    float ax = 0.f, ay = 0.f;
    for (int c = 0; c < NC; ++c) {
        ax += xc2w[c] * xf[(b * NC + c) * NE + t];
        ay += yc2w[c] * yf[(b * NC + c) * NE + t];
    }
    sXs[t] = ax + xc2b[0];
    sYo[t] = ay + yc2b[0];
    if (t < 10) {
        float s = 0.f;
        for (int d = 0; d < 32; ++d) s += etab[t * 32 + d] * econv[d];
        sEd[t] = lk(s);
    }
    __syncthreads();
    for (int i = 0; i < NE; ++i) {
        int idx = (b * NE + i) * NE + t;
        float L = lk(sXs[t] + sYo[i]);
        Lw[idx] = L;
        gb[idx] = L + sEd[edge_mat[idx]] + m_bias[idx];
    }
}

// ---------------- K2: per (b,e): local -> A (row sm) / A2 (col sm) -> x_ret, y_ret (bf16 to ws)
__global__ __launch_bounds__(256) void k_attn(const float* __restrict__ Lw,
                                              const float* __restrict__ xfw, const float* __restrict__ yfw,
                                              const int* __restrict__ path_mat, const float* __restrict__ p_bias,
                                              const float* __restrict__ ptab, const float* __restrict__ pconv,
                                              u16* __restrict__ xret, u16* __restrict__ yret) {
    int b = blockIdx.x >> 6, e = blockIdx.x & 63;
    int t = threadIdx.x;
    __shared__ float sA[4096];     // local -> A[m][n]
    __shared__ float sA2[4096];    // A2[n][m]
    __shared__ float sTf[128 * 65]; // operand tile [c][n], +1 pad: both R/W 2-way (free)
    __shared__ float sRed[256];    // rmax, rinv, cmax, cinv
    __shared__ float sPdot[20];

    if (t < 20) {
        float s = 0.f;
        for (int d = 0; d < 32; ++d) s += ptab[t * 32 + d] * pconv[d];
        sPdot[t] = lk(s);
    }
    __syncthreads();

    // phase 1: local[m][n] = L[b,m,n] + pdot[path] + p_bias
    {
        int m = t >> 2, n0 = (t & 3) * 16;
        int base = (((b * 64 + e) * 64 + m) * 64 + n0);
        const int4* pm4 = (const int4*)(path_mat + base);
        const float4* pb4 = (const float4*)(p_bias + base);
        const float4* L4 = (const float4*)(Lw + (b * 64 + m) * 64 + n0);
        float4* dst = (float4*)(sA + m * 64 + n0);
#pragma unroll
        for (int q = 0; q < 4; ++q) {
            int4 pm = pm4[q]; float4 pb = pb4[q]; float4 l = L4[q];
            float4 v;
            v.x = l.x + sPdot[pm.x] + pb.x;
            v.y = l.y + sPdot[pm.y] + pb.y;
            v.z = l.z + sPdot[pm.z] + pb.z;
            v.w = l.w + sPdot[pm.w] + pb.w;
            dst[q] = v;
        }
    }
    __syncthreads();

    // phase 2: row stats (t<64) and column stats (64<=t<128)
    if (t < 64) {
        const float4* rp = (const float4*)(sA + t * 64);
        float mx = -1e30f;
        for (int k = 0; k < 16; ++k) {
            float4 v = rp[k];
            mx = fmaxf(mx, fmaxf(fmaxf(v.x, v.y), fmaxf(v.z, v.w)));
        }
        float s = 0.f;
        for (int k = 0; k < 16; ++k) {
            float4 v = rp[k];
            s += __expf(v.x - mx) + __expf(v.y - mx) + __expf(v.z - mx) + __expf(v.w - mx);
        }
        sRed[t] = mx; sRed[64 + t] = 1.f / s;
    } else if (t < 128) {
        int n = t - 64;
        float mx = -1e30f;
        for (int m = 0; m < 64; ++m) mx = fmaxf(mx, sA[m * 64 + n]);
        float s = 0.f;
        for (int m = 0; m < 64; ++m) s += __expf(sA[m * 64 + n] - mx);
        sRed[128 + n] = mx; sRed[192 + n] = 1.f / s;
    }
    __syncthreads();

    // phase 3: A in place, A2 transposed
    {
        int m = t >> 2, n0 = (t & 3) * 16;
        float rmax = sRed[m], rinv = sRed[64 + m];
        float4* rowp = (float4*)(sA + m * 64 + n0);
#pragma unroll
        for (int q = 0; q < 4; ++q) {
            float4 v = rowp[q];
            int n = n0 + q * 4;
            sA2[(n + 0) * 64 + m] = __expf(v.x - sRed[128 + n + 0]) * sRed[192 + n + 0];
            sA2[(n + 1) * 64 + m] = __expf(v.y - sRed[128 + n + 1]) * sRed[192 + n + 1];
            sA2[(n + 2) * 64 + m] = __expf(v.z - sRed[128 + n + 2]) * sRed[192 + n + 2];
            sA2[(n + 3) * 64 + m] = __expf(v.w - sRed[128 + n + 3]) * sRed[192 + n + 3];
            float4 a;
            a.x = __expf(v.x - rmax) * rinv; a.y = __expf(v.y - rmax) * rinv;
            a.z = __expf(v.z - rmax) * rinv; a.w = __expf(v.w - rmax) * rinv;
            rowp[q] = a;
        }
    }
    __syncthreads();

    // phase 4: stage yf fp32: sTf[c*65+n]
    {
        const float* src = yfw + b * NC * NE;
#pragma unroll 4
        for (int k = 0; k < 32; ++k) {
            int idx = k * 256 + t; int c = idx >> 6, n = idx & 63;
            sTf[c * 65 + n] = src[idx];
        }
    }
    __syncthreads();

    int c = t & 127, half = t >> 7, r0 = half * 32;
    float acc[32];

    // phase 5: S_x[m] = sum_n A[m][n] * yf[c][n]; xret = leaky(S_x + xf[c][m])
#pragma unroll
    for (int k = 0; k < 32; ++k) acc[k] = 0.f;
    for (int nc = 0; nc < 4; ++nc) {
        int n0 = nc * 16;
        float yv[16];
#pragma unroll
        for (int k = 0; k < 16; ++k) yv[k] = sTf[c * 65 + n0 + k];
#pragma unroll
        for (int mm = 0; mm < 32; ++mm) {
            const float4* ap = (const float4*)(sA + (r0 + mm) * 64 + n0);
            float4 a0 = ap[0], a1 = ap[1], a2 = ap[2], a3 = ap[3];
            acc[mm] += a0.x * yv[0] + a0.y * yv[1] + a0.z * yv[2] + a0.w * yv[3]
                     + a1.x * yv[4] + a1.y * yv[5] + a1.z * yv[6] + a1.w * yv[7]
                     + a2.x * yv[8] + a2.y * yv[9] + a2.z * yv[10] + a2.w * yv[11]
                     + a3.x * yv[12] + a3.y * yv[13] + a3.z * yv[14] + a3.w * yv[15];
        }
    }
    {
        const float* xfp = xfw + b * NC * NE + c * 64 + r0;
        u32* op = (u32*)(xret + (((b * NC + c) * 64 + e) * 64 + r0));
#pragma unroll
        for (int k = 0; k < 16; ++k) {
            float v0 = lk(acc[2 * k] + xfp[2 * k]);
            float v1 = lk(acc[2 * k + 1] + xfp[2 * k + 1]);
            op[k] = (u32)f2b(v0) | ((u32)f2b(v1) << 16);
        }
    }
    __syncthreads();

    // phase 6: stage xf (rows = m)
    {
        const float* src = xfw + b * NC * NE;
#pragma unroll 4
        for (int k = 0; k < 32; ++k) {
            int idx = k * 256 + t; int cc = idx >> 6, m = idx & 63;
            sTf[cc * 65 + m] = src[idx];
        }
    }
    __syncthreads();

    // phase 7: S_y[n] = sum_m A2[n][m] * xf[c][m]; yret = leaky(S_y + yf[c][n])
#pragma unroll
    for (int k = 0; k < 32; ++k) acc[k] = 0.f;
    for (int mc = 0; mc < 4; ++mc) {
        int m0 = mc * 16;
        float xv[16];
#pragma unroll
        for (int k = 0; k < 16; ++k) xv[k] = sTf[c * 65 + m0 + k];
#pragma unroll
        for (int nn = 0; nn < 32; ++nn) {
            const float4* ap = (const float4*)(sA2 + (r0 + nn) * 64 + m0);
            float4 a0 = ap[0], a1 = ap[1], a2 = ap[2], a3 = ap[3];
            acc[nn] += a0.x * xv[0] + a0.y * xv[1] + a0.z * xv[2] + a0.w * xv[3]
                     + a1.x * xv[4] + a1.y * xv[5] + a1.z * xv[6] + a1.w * xv[7]
                     + a2.x * xv[8] + a2.y * xv[9] + a2.z * xv[10] + a2.w * xv[11]
                     + a3.x * xv[12] + a3.y * xv[13] + a3.z * xv[14] + a3.w * xv[15];
        }
    }
    {
        const float* yfp = yfw + b * NC * NE + c * 64 + r0;
        u32* op = (u32*)(yret + (((b * NC + c) * 64 + e) * 64 + r0));
#pragma unroll
        for (int k = 0; k < 16; ++k) {
            float v0 = lk(acc[2 * k] + yfp[2 * k]);
            float v1 = lk(acc[2 * k + 1] + yfp[2 * k + 1]);
            op[k] = (u32)f2b(v0) | ((u32)f2b(v1) << 16);
        }
    }
}

// ---------------- K2b: conv1 (1x1, 384->128): h[b,o,i,j] = leaky(sum_c w1[o,c] men[b,c,i,j] + b1[o])
__global__ __launch_bounds__(256) void k_conv1(const u16* __restrict__ xret, const u16* __restrict__ yret,
                                               const float* __restrict__ pre, const float* __restrict__ wT1,
                                               const float* __restrict__ b1, u16* __restrict__ h) {
    int b = blockIdx.x >> 6, i = blockIdx.x & 63;
    int t = threadIdx.x;
    int o = t & 127, jh = t >> 7, j0 = jh * 32;
    __shared__ float sM[32 * 64];
    float acc[32];
    float bias = b1[o];
#pragma unroll
    for (int k = 0; k < 32; ++k) acc[k] = bias;
    for (int ch = 0; ch < 12; ++ch) {
        int c1 = ch * 32;
        __syncthreads();
#pragma unroll
        for (int k = 0; k < 8; ++k) {
            int idx = k * 256 + t; int cc = idx >> 6, j = idx & 63;
            int cg = c1 + cc;
            float v;
            if (cg < 128)      v = b2f(xret[(((b * NC + cg) * 64 + i) * 64 + j)]);
            else if (cg < 256) v = b2f(yret[(((b * NC + (cg - 128)) * 64 + i) * 64 + j)]);
            else               v = pre[(((b * NC + (cg - 256)) * 64 + i) * 64 + j)];
            sM[idx] = v;
        }
        __syncthreads();
        for (int cc = 0; cc < 32; ++cc) {
            float w = wT1[(c1 + cc) * 128 + o];
            const float* row = sM + cc * 64 + j0;    // wave-uniform address -> broadcast
#pragma unroll
            for (int k = 0; k < 32; ++k) acc[k] += w * row[k];
        }
    }
    u32* op = (u32*)(h + (((b * NC + o) * 64 + i) * 64 + j0));
#pragma unroll
    for (int k = 0; k < 16; ++k) {
        float v0 = lk(acc[2 * k]), v1 = lk(acc[2 * k + 1]);
        op[k] = (u32)f2b(v0) | ((u32)f2b(v1) << 16);
    }
}

// ---------------- K3: conv2 (3x3 SAME, 128->128): men2rel -> d_out (fp32)
__global__ __launch_bounds__(256) void k_conv2(const u16* __restrict__ h, const float* __restrict__ wT2,
                                               const float* __restrict__ b2, float* __restrict__ out_m2r) {
    int b = blockIdx.x >> 6, i = blockIdx.x & 63;
    int t = threadIdx.x;
    int o = t & 127, jh = t >> 7, j0 = jh * 32;
    __shared__ float sH[16 * 3 * 72];   // rows padded: col 0..3 / 68..71 zero (jj = col-4)
    float acc[32];
    float bias = b2[o];
#pragma unroll
    for (int k = 0; k < 32; ++k) acc[k] = bias;
    for (int ch = 0; ch < 8; ++ch) {
        int c0 = ch * 16;
        __syncthreads();
        for (int k = 0; k < 14; ++k) {
            int idx = k * 256 + t;
            if (idx < 3456) {
                int cc = idx / 216; int rem = idx - cc * 216;
                int r = rem / 72; int col = rem - r * 72;
                int ir = i + r - 1, jj = col - 4;
                float v = 0.f;
                if (ir >= 0 && ir < 64 && jj >= 0 && jj < 64)
                    v = b2f(h[((b * NC + c0 + cc) * 64 + ir) * 64 + jj]);
                sH[idx] = v;
            }
        }
        __syncthreads();
        for (int cc = 0; cc < 16; ++cc) {
            int cg = c0 + cc;
            float w[9];
#pragma unroll
            for (int q = 0; q < 9; ++q) w[q] = wT2[(cg * 9 + q) * 128 + o];
#pragma unroll
            for (int di = 0; di < 3; ++di) {
                const float4* rp = (const float4*)(sH + (cc * 3 + di) * 72 + j0);
                float v[40];
#pragma unroll
                for (int q = 0; q < 10; ++q) {
                    float4 f = rp[q];
                    v[4 * q] = f.x; v[4 * q + 1] = f.y; v[4 * q + 2] = f.z; v[4 * q + 3] = f.w;
                }
#pragma unroll
                for (int dj = 0; dj < 3; ++dj) {
                    float wv = w[di * 3 + dj];
#pragma unroll
                    for (int jr = 0; jr < 32; ++jr) acc[jr] += wv * v[jr + dj + 3];
                }
            }
        }
    }
    float* op = out_m2r + (((b * NC + o) * 64 + i) * 64 + j0);
#pragma unroll
    for (int k = 0; k < 32; ++k) op[k] = lk(acc[k]);
}

// ---------------- K3b: scores + g = gbase + leaky(score_w . men2rel)
__global__ __launch_bounds__(64) void k_scores(const float* __restrict__ m2r, const float* __restrict__ score_w,
                                               const float* __restrict__ gb, float* __restrict__ g) {
    int b = blockIdx.x >> 6, i = blockIdx.x & 63;
    int j = threadIdx.x;
    float s = 0.f;
    for (int o = 0; o < NC; ++o)
        s += score_w[o] * m2r[((b * NC + o) * 64 + i) * 64 + j];
    int idx = (b * 64 + i) * 64 + j;
    g[idx] = gb[idx] + lk(s);
}

// ---------------- K4: out_x / out_y: softmax(g) row/col, GEMV vs y_lin/x_lin, + residual
__global__ __launch_bounds__(128) void k_out(const float* __restrict__ g,
                                             const float* __restrict__ xl, const float* __restrict__ yl,
                                             const float* __restrict__ x, const float* __restrict__ y,
                                             float* __restrict__ out) {
    int blk = blockIdx.x;
    int which = blk >> 9; int r = blk & 511;
    int b = r >> 6, row = r & 63;
    int t = threadIdx.x;
    __shared__ float sW[64];
    if (t < 64) {
        float v = which ? g[(b * 64 + t) * 64 + row] : g[(b * 64 + row) * 64 + t];
        float mx = v;
        for (int off = 32; off > 0; off >>= 1) mx = fmaxf(mx, __shfl_xor(mx, off));
        float e = __expf(v - mx);
        float s = e;
        for (int off = 32; off > 0; off >>= 1) s += __shfl_xor(s, off);
        sW[t] = e / s;
    }
    __syncthreads();
    const float* lin = which ? xl : yl;
    const float* res = which ? y : x;
    float acc = 0.f;
#pragma unroll 4
    for (int k = 0; k < 64; ++k) acc += sW[k] * lin[(b * 64 + k) * NC + t];
    float ov = acc + res[(b * NC + t) * 64 + row];
    out[(which ? 65536 : 0) + (b * NC + t) * 64 + row] = ov;
}

extern "C" void kernel_launch(void* const* d_in, const int* in_sizes, int n_in,
                              void* d_out, int out_size, void* d_ws, size_t ws_size,
                              hipStream_t stream) {
    const float* x = (const float*)d_in[0];
    const float* y = (const float*)d_in[1];
    const float* m_bias = (const float*)d_in[2];
    const int* edge_mat = (const int*)d_in[3];
    const float* p_bias = (const float*)d_in[4];
    const int* path_mat = (const int*)d_in[5];
    const float* pre = (const float*)d_in[6];
    const float* xc1 = (const float*)d_in[7];
    const float* yc1 = (const float*)d_in[8];
    const float* xc2w = (const float*)d_in[9];
    const float* xc2b = (const float*)d_in[10];
    const float* yc2w = (const float*)d_in[11];
    const float* yc2b = (const float*)d_in[12];
    const float* pconv = (const float*)d_in[13];
    const float* econv = (const float*)d_in[14];
    const float* w1 = (const float*)d_in[15];
    const float* b1 = (const float*)d_in[16];
    const float* w2 = (const float*)d_in[17];
    const float* b2 = (const float*)d_in[18];
    const float* score_w = (const float*)d_in[19];
    const float* xlw = (const float*)d_in[20];
    const float* ylw = (const float*)d_in[21];
    const float* etab = (const float*)d_in[22];
    const float* ptab = (const float*)d_in[23];

    float* xf = (float*)d_ws;               // 65536 f
    float* yf = xf + 65536;                 // 65536 f
    float* xl = yf + 65536;                 // 65536 f
    float* yl = xl + 65536;                 // 65536 f
    float* Lw = yl + 65536;                 // 32768 f
    float* gb = Lw + 32768;                 // 32768 f
    float* g = gb + 32768;                  // 32768 f
    float* wT1 = g + 32768;                 // 49152 f
    float* wT2 = wT1 + 49152;               // 147456 f
    u16* xret = (u16*)(wT2 + 147456);       // 4194304 bf16
    u16* yret = xret + 4194304;             // 4194304 bf16
    u16* hbuf = yret + 4194304;             // 4194304 bf16   total ~26.1 MiB

    float* out = (float*)d_out;
    float* out_m2r = out + 131072;

    hipLaunchKernelGGL(k_prep, dim3(768), dim3(256), 0, stream, w1, w2, wT1, wT2);
    hipLaunchKernelGGL(k_feat, dim3(2048), dim3(64), 0, stream, x, y, xc1, yc1, xf, yf);
    hipLaunchKernelGGL(k_lin, dim3(1024), dim3(128), 0, stream, x, y, xlw, ylw, xl, yl);
    hipLaunchKernelGGL(k_selfother, dim3(8), dim3(64), 0, stream, xf, yf, xc2w, xc2b, yc2w, yc2b,
                       etab, econv, edge_mat, m_bias, Lw, gb);
    hipLaunchKernelGGL(k_attn, dim3(512), dim3(256), 0, stream, Lw, xf, yf, path_mat, p_bias,
                       ptab, pconv, xret, yret);
    hipLaunchKernelGGL(k_conv1, dim3(512), dim3(256), 0, stream, xret, yret, pre, wT1, b1, hbuf);
    hipLaunchKernelGGL(k_conv2, dim3(512), dim3(256), 0, stream, hbuf, wT2, b2, out_m2r);
    hipLaunchKernelGGL(k_scores, dim3(512), dim3(64), 0, stream, out_m2r, score_w, gb, g);
    hipLaunchKernelGGL(k_out, dim3(1024), dim3(128), 0, stream, g, xl, yl, x, y, out);
}

// Round 3
// 252.756 us; speedup vs baseline: 2.0286x; 2.0286x over previous
//
#include <hip/hip_runtime.h>
#include <hip/hip_bf16.h>

// B=8, E=64, CIN=C=PRE=128, DME=DEN=32, edge types 10, path types 20.
// fp32 I/O; internal bf16 intermediates (xret/yret/hT) + bf16 MFMA for conv1/conv2.

typedef unsigned short u16;
typedef unsigned int u32;
typedef short s16x8 __attribute__((ext_vector_type(8)));
typedef float f32x4 __attribute__((ext_vector_type(4)));

#define NB 8
#define NE 64
#define NC 128

__device__ __forceinline__ float b2f(u16 u) { return __uint_as_float(((u32)u) << 16); }
__device__ __forceinline__ u16 f2b(float f) {
    u32 x = __float_as_uint(f);
    u32 r = (x + 0x7fffu + ((x >> 16) & 1u)) >> 16;   // RNE
    return (u16)r;
}
__device__ __forceinline__ float lk(float v) { return v >= 0.f ? v : 0.1f * v; }

// ---------------- K0: weights -> bf16 MFMA A-fragment order
// wA1[((kc*8+mtg)*64+lane)*8+e] = w1[o=mtg*16+(lane&15)][c=kc*32+(lane>>4)*8+e], kc<12
// wA2[(((tap*4+kc)*8+mtg)*64+lane)*8+e] = w2[o][c][di][dj], tap=di*3+dj, kc<4
__global__ __launch_bounds__(256) void k_prepw(const float* __restrict__ w1, const float* __restrict__ w2,
                                               u16* __restrict__ wA1, u16* __restrict__ wA2) {
    int idx = blockIdx.x * 256 + threadIdx.x;
    if (idx < 49152) {
        int e = idx & 7, lane = (idx >> 3) & 63, mtg = (idx >> 9) & 7, kc = idx >> 12;
        int o = mtg * 16 + (lane & 15), c = kc * 32 + ((lane >> 4) << 3) + e;
        wA1[idx] = f2b(w1[o * 384 + c]);
    } else {
        int id2 = idx - 49152;
        if (id2 < 147456) {
            int e = id2 & 7, lane = (id2 >> 3) & 63, mtg = (id2 >> 9) & 7;
            int kc = (id2 >> 12) & 3, tap = id2 >> 14;
            int o = mtg * 16 + (lane & 15), c = kc * 32 + ((lane >> 4) << 3) + e;
            wA2[id2] = f2b(w2[(o * 128 + c) * 9 + tap]);
        }
    }
}

// ---------------- K1: x_f[b,c,m] = sum_i xc1_w[c,i] x[b,i,m]  (and y_f)
__global__ __launch_bounds__(64) void k_feat(const float* __restrict__ x, const float* __restrict__ y,
                                             const float* __restrict__ xc1, const float* __restrict__ yc1,
                                             float* __restrict__ xf, float* __restrict__ yf) {
    int blk = blockIdx.x;
    int which = blk >> 10; int r = blk & 1023;
    int b = r >> 7, c = r & 127;
    const float* in = which ? y : x;
    const float* w = which ? yc1 : xc1;
    float* out = which ? yf : xf;
    int m = threadIdx.x;
    const float* wr = w + c * NC;
    const float* ib = in + b * NC * NE + m;
    float acc = 0.f;
#pragma unroll 8
    for (int i = 0; i < NC; ++i) acc += wr[i] * ib[i * NE];
    out[(b * NC + c) * NE + m] = acc;
}

// ---------------- K1L: x_lin[b,m,i] = sum_j xlin_w[i,j] x[b,j,m]
__global__ __launch_bounds__(128) void k_lin(const float* __restrict__ x, const float* __restrict__ y,
                                             const float* __restrict__ xlw, const float* __restrict__ ylw,
                                             float* __restrict__ xl, float* __restrict__ yl) {
    int blk = blockIdx.x;
    int which = blk >> 9; int r = blk & 511;
    int b = r >> 6, ent = r & 63;
    const float* in = which ? y : x;
    const float* w = which ? ylw : xlw;
    float* out = which ? yl : xl;
    int i = threadIdx.x;
    float acc = 0.f;
#pragma unroll 4
    for (int j = 0; j < NC; ++j) acc += w[i * NC + j] * in[(b * NC + j) * NE + ent];
    out[(b * NE + ent) * NC + i] = acc;
}

// ---------------- K1b: L=leaky(xs[j]+yo[i]), gbase = L + edge + m_bias
__global__ __launch_bounds__(64) void k_selfother(const float* __restrict__ xf, const float* __restrict__ yf,
                                                  const float* __restrict__ xc2w, const float* __restrict__ xc2b,
                                                  const float* __restrict__ yc2w, const float* __restrict__ yc2b,
                                                  const float* __restrict__ etab, const float* __restrict__ econv,
                                                  const int* __restrict__ edge_mat, const float* __restrict__ m_bias,
                                                  float* __restrict__ Lw, float* __restrict__ gb) {
    int b = blockIdx.x; int t = threadIdx.x;
    __shared__ float sXs[64], sYo[64], sEd[16];
    float ax = 0.f, ay = 0.f;
    for (int c = 0; c < NC; ++c) {
        ax += xc2w[c] * xf[(b * NC + c) * NE + t];
        ay += yc2w[c] * yf[(b * NC + c) * NE + t];
    }
    sXs[t] = ax + xc2b[0];
    sYo[t] = ay + yc2b[0];
    if (t < 10) {
        float s = 0.f;
        for (int d = 0; d < 32; ++d) s += etab[t * 32 + d] * econv[d];
        sEd[t] = lk(s);
    }
    __syncthreads();
    for (int i = 0; i < NE; ++i) {
        int idx = (b * NE + i) * NE + t;
        float L = lk(sXs[t] + sYo[i]);
        Lw[idx] = L;
        gb[idx] = L + sEd[edge_mat[idx]] + m_bias[idx];
    }
}

// ---------------- K2: per (b,e) attention (unchanged from passing R2 version)
__global__ __launch_bounds__(256) void k_attn(const float* __restrict__ Lw,
                                              const float* __restrict__ xfw, const float* __restrict__ yfw,
                                              const int* __restrict__ path_mat, const float* __restrict__ p_bias,
                                              const float* __restrict__ ptab, const float* __restrict__ pconv,
                                              u16* __restrict__ xret, u16* __restrict__ yret) {
    int b = blockIdx.x >> 6, e = blockIdx.x & 63;
    int t = threadIdx.x;
    __shared__ float sA[4096];
    __shared__ float sA2[4096];
    __shared__ float sTf[128 * 65];
    __shared__ float sRed[256];
    __shared__ float sPdot[20];

    if (t < 20) {
        float s = 0.f;
        for (int d = 0; d < 32; ++d) s += ptab[t * 32 + d] * pconv[d];
        sPdot[t] = lk(s);
    }
    __syncthreads();

    {
        int m = t >> 2, n0 = (t & 3) * 16;
        int base = (((b * 64 + e) * 64 + m) * 64 + n0);
        const int4* pm4 = (const int4*)(path_mat + base);
        const float4* pb4 = (const float4*)(p_bias + base);
        const float4* L4 = (const float4*)(Lw + (b * 64 + m) * 64 + n0);
        float4* dst = (float4*)(sA + m * 64 + n0);
#pragma unroll
        for (int q = 0; q < 4; ++q) {
            int4 pm = pm4[q]; float4 pb = pb4[q]; float4 l = L4[q];
            float4 v;
            v.x = l.x + sPdot[pm.x] + pb.x;
            v.y = l.y + sPdot[pm.y] + pb.y;
            v.z = l.z + sPdot[pm.z] + pb.z;
            v.w = l.w + sPdot[pm.w] + pb.w;
            dst[q] = v;
        }
    }
    __syncthreads();

    if (t < 64) {
        const float4* rp = (const float4*)(sA + t * 64);
        float mx = -1e30f;
        for (int k = 0; k < 16; ++k) {
            float4 v = rp[k];
            mx = fmaxf(mx, fmaxf(fmaxf(v.x, v.y), fmaxf(v.z, v.w)));
        }
        float s = 0.f;
        for (int k = 0; k < 16; ++k) {
            float4 v = rp[k];
            s += __expf(v.x - mx) + __expf(v.y - mx) + __expf(v.z - mx) + __expf(v.w - mx);
        }
        sRed[t] = mx; sRed[64 + t] = 1.f / s;
    } else if (t < 128) {
        int n = t - 64;
        float mx = -1e30f;
        for (int m = 0; m < 64; ++m) mx = fmaxf(mx, sA[m * 64 + n]);
        float s = 0.f;
        for (int m = 0; m < 64; ++m) s += __expf(sA[m * 64 + n] - mx);
        sRed[128 + n] = mx; sRed[192 + n] = 1.f / s;
    }
    __syncthreads();

    {
        int m = t >> 2, n0 = (t & 3) * 16;
        float rmax = sRed[m], rinv = sRed[64 + m];
        float4* rowp = (float4*)(sA + m * 64 + n0);
#pragma unroll
        for (int q = 0; q < 4; ++q) {
            float4 v = rowp[q];
            int n = n0 + q * 4;
            sA2[(n + 0) * 64 + m] = __expf(v.x - sRed[128 + n + 0]) * sRed[192 + n + 0];
            sA2[(n + 1) * 64 + m] = __expf(v.y - sRed[128 + n + 1]) * sRed[192 + n + 1];
            sA2[(n + 2) * 64 + m] = __expf(v.z - sRed[128 + n + 2]) * sRed[192 + n + 2];
            sA2[(n + 3) * 64 + m] = __expf(v.w - sRed[128 + n + 3]) * sRed[192 + n + 3];
            float4 a;
            a.x = __expf(v.x - rmax) * rinv; a.y = __expf(v.y - rmax) * rinv;
            a.z = __expf(v.z - rmax) * rinv; a.w = __expf(v.w - rmax) * rinv;
            rowp[q] = a;
        }
    }
    __syncthreads();

    {
        const float* src = yfw + b * NC * NE;
#pragma unroll 4
        for (int k = 0; k < 32; ++k) {
            int idx = k * 256 + t; int c = idx >> 6, n = idx & 63;
            sTf[c * 65 + n] = src[idx];
        }
    }
    __syncthreads();

    int c = t & 127, half = t >> 7, r0 = half * 32;
    float acc[32];

#pragma unroll
    for (int k = 0; k < 32; ++k) acc[k] = 0.f;
    for (int nc = 0; nc < 4; ++nc) {
        int n0 = nc * 16;
        float yv[16];
#pragma unroll
        for (int k = 0; k < 16; ++k) yv[k] = sTf[c * 65 + n0 + k];
#pragma unroll
        for (int mm = 0; mm < 32; ++mm) {
            const float4* ap = (const float4*)(sA + (r0 + mm) * 64 + n0);
            float4 a0 = ap[0], a1 = ap[1], a2 = ap[2], a3 = ap[3];
            acc[mm] += a0.x * yv[0] + a0.y * yv[1] + a0.z * yv[2] + a0.w * yv[3]
                     + a1.x * yv[4] + a1.y * yv[5] + a1.z * yv[6] + a1.w * yv[7]
                     + a2.x * yv[8] + a2.y * yv[9] + a2.z * yv[10] + a2.w * yv[11]
                     + a3.x * yv[12] + a3.y * yv[13] + a3.z * yv[14] + a3.w * yv[15];
        }
    }
    {
        const float* xfp = xfw + b * NC * NE + c * 64 + r0;
        u32* op = (u32*)(xret + (((b * NC + c) * 64 + e) * 64 + r0));
#pragma unroll
        for (int k = 0; k < 16; ++k) {
            float v0 = lk(acc[2 * k] + xfp[2 * k]);
            float v1 = lk(acc[2 * k + 1] + xfp[2 * k + 1]);
            op[k] = (u32)f2b(v0) | ((u32)f2b(v1) << 16);
        }
    }
    __syncthreads();

    {
        const float* src = xfw + b * NC * NE;
#pragma unroll 4
        for (int k = 0; k < 32; ++k) {
            int idx = k * 256 + t; int cc = idx >> 6, m = idx & 63;
            sTf[cc * 65 + m] = src[idx];
        }
    }
    __syncthreads();

#pragma unroll
    for (int k = 0; k < 32; ++k) acc[k] = 0.f;
    for (int mc = 0; mc < 4; ++mc) {
        int m0 = mc * 16;
        float xv[16];
#pragma unroll
        for (int k = 0; k < 16; ++k) xv[k] = sTf[c * 65 + m0 + k];
#pragma unroll
        for (int nn = 0; nn < 32; ++nn) {
            const float4* ap = (const float4*)(sA2 + (r0 + nn) * 64 + m0);
            float4 a0 = ap[0], a1 = ap[1], a2 = ap[2], a3 = ap[3];
            acc[nn] += a0.x * xv[0] + a0.y * xv[1] + a0.z * xv[2] + a0.w * xv[3]
                     + a1.x * xv[4] + a1.y * xv[5] + a1.z * xv[6] + a1.w * xv[7]
                     + a2.x * xv[8] + a2.y * xv[9] + a2.z * xv[10] + a2.w * xv[11]
                     + a3.x * xv[12] + a3.y * xv[13] + a3.z * xv[14] + a3.w * xv[15];
        }
    }
    {
        const float* yfp = yfw + b * NC * NE + c * 64 + r0;
        u32* op = (u32*)(yret + (((b * NC + c) * 64 + e) * 64 + r0));
#pragma unroll
        for (int k = 0; k < 16; ++k) {
            float v0 = lk(acc[2 * k] + yfp[2 * k]);
            float v1 = lk(acc[2 * k + 1] + yfp[2 * k + 1]);
            op[k] = (u32)f2b(v0) | ((u32)f2b(v1) << 16);
        }
    }
}

// ---------------- K3: conv1 (1x1, 384->128) via MFMA -> hT[b][i][j][o] bf16
// block=(b,i): 128o x 64j; 4 waves: wm=o-half, wn=j-half; wave tile 4m x 2n.
__global__ __launch_bounds__(256) void k_conv1(const u16* __restrict__ xret, const u16* __restrict__ yret,
                                               const float* __restrict__ pre, const u16* __restrict__ wA1,
                                               const float* __restrict__ b1, u16* __restrict__ hT) {
    int b = blockIdx.x >> 6, i = blockIdx.x & 63;
    int t = threadIdx.x;
    int lane = t & 63, w = t >> 6, wm = w & 1, wn = w >> 1, kg = lane >> 4;
    __shared__ u16 sB1[64][392];   // [j][swizzled c], stride 392 (16B-mult); XOR-(j>>3) 8-elem swizzle

    // stage all K=384: pass p: c = p*32 + (t>>3), 8 j's at jg=t&7
    for (int p = 0; p < 12; ++p) {
        int c = p * 32 + (t >> 3);
        int jg = t & 7, j0 = jg * 8;
        s16x8 vv;
        if (c < 128) {
            vv = *(const s16x8*)(xret + (b * 128 + c) * 4096 + i * 64 + j0);
        } else if (c < 256) {
            vv = *(const s16x8*)(yret + (b * 128 + (c - 128)) * 4096 + i * 64 + j0);
        } else {
            const float4* s4 = (const float4*)(pre + (b * 128 + (c - 256)) * 4096 + i * 64 + j0);
            float4 f0 = s4[0], f1 = s4[1];
            vv[0] = (short)f2b(f0.x); vv[1] = (short)f2b(f0.y);
            vv[2] = (short)f2b(f0.z); vv[3] = (short)f2b(f0.w);
            vv[4] = (short)f2b(f1.x); vv[5] = (short)f2b(f1.y);
            vv[6] = (short)f2b(f1.z); vv[7] = (short)f2b(f1.w);
        }
        int cs = (((c >> 3) ^ jg) << 3) + (c & 7);   // j>>3 == jg for this thread
#pragma unroll
        for (int jj = 0; jj < 8; ++jj) sB1[j0 + jj][cs] = (u16)vv[jj];
    }
    __syncthreads();

    f32x4 acc[4][2];
#pragma unroll
    for (int mt = 0; mt < 4; ++mt)
#pragma unroll
        for (int nt = 0; nt < 2; ++nt) acc[mt][nt] = (f32x4)(0.f);

    for (int kc = 0; kc < 12; ++kc) {
        s16x8 af[4];
#pragma unroll
        for (int mt = 0; mt < 4; ++mt)
            af[mt] = *(const s16x8*)(wA1 + (((kc * 8 + wm * 4 + mt) * 64 + lane) << 3));
        s16x8 bf[2];
#pragma unroll
        for (int nt = 0; nt < 2; ++nt) {
            int n = wn * 32 + nt * 16 + (lane & 15);
            bf[nt] = *(const s16x8*)(&sB1[n][(((kc << 2) | kg) ^ (n >> 3)) << 3]);
        }
#pragma unroll
        for (int mt = 0; mt < 4; ++mt)
#pragma unroll
            for (int nt = 0; nt < 2; ++nt)
                acc[mt][nt] = __builtin_amdgcn_mfma_f32_16x16x32_bf16(af[mt], bf[nt], acc[mt][nt], 0, 0, 0);
    }

    // epilogue: hT[b][i][j][o] = bf16(lk(acc + b1[o]))
#pragma unroll
    for (int mt = 0; mt < 4; ++mt) {
        int o0 = wm * 64 + mt * 16 + (lane >> 4) * 4;
        float4 bb = *(const float4*)(b1 + o0);
#pragma unroll
        for (int nt = 0; nt < 2; ++nt) {
            int j = wn * 32 + nt * 16 + (lane & 15);
            f32x4 a = acc[mt][nt];
            u32 lo = (u32)f2b(lk(a[0] + bb.x)) | ((u32)f2b(lk(a[1] + bb.y)) << 16);
            u32 hi = (u32)f2b(lk(a[2] + bb.z)) | ((u32)f2b(lk(a[3] + bb.w)) << 16);
            u32* dst = (u32*)(hT + ((b * 64 + i) * 64 + j) * 128 + o0);
            dst[0] = lo; dst[1] = hi;
        }
    }
}

// ---------------- K4: conv2 (3x3 SAME) via MFMA; writes men2rel (fp32 d_out) + fused scores -> g
// block=(b, i-pair): 128o x (2 rows x 64 j); wave: wm=o-half, wn=row; tile 4m x 4n.
__global__ __launch_bounds__(256) void k_conv2(const u16* __restrict__ hT, const u16* __restrict__ wA2,
                                               const float* __restrict__ b2, const float* __restrict__ score_w,
                                               const float* __restrict__ gb, float* __restrict__ m2r,
                                               float* __restrict__ g) {
    int b = blockIdx.x >> 5, ip = blockIdx.x & 31;
    int i0 = ip * 2;
    int t = threadIdx.x;
    int lane = t & 63, w = t >> 6, wm = w & 1, wn = w >> 1;
    __shared__ u16 sB2[4][66][136];   // [row i0-1..i0+2][j+1 (halo 0,65)][c]
    __shared__ float sSc[2][2][64];   // [wm][row][j]

    // zero halo columns j'=0 and j'=65
#pragma unroll
    for (int q = 0; q < 2; ++q) {
        int u = q * 256 + t;             // 512 u32 slots
        int r = u >> 7, hcol = (u >> 6) & 1, c2 = u & 63;
        *(u32*)&sB2[r][hcol ? 65 : 0][c2 * 2] = 0u;
    }
    // core staging: 4 rows x 64 j x 128 c, dwordx4 units
    for (int it = 0; it < 16; ++it) {
        int u = it * 256 + t;
        int cg = u & 15, j = (u >> 4) & 63, r = u >> 10;
        int ir = i0 - 1 + r;
        int4 v = make_int4(0, 0, 0, 0);
        if (ir >= 0 && ir < 64)
            v = *(const int4*)(hT + ((b * 64 + ir) * 64 + j) * 128 + cg * 8);
        *(int4*)&sB2[r][j + 1][cg * 8] = v;
    }
    __syncthreads();

    f32x4 acc[4][4];
#pragma unroll
    for (int mt = 0; mt < 4; ++mt)
#pragma unroll
        for (int nt = 0; nt < 4; ++nt) acc[mt][nt] = (f32x4)(0.f);

    for (int kc = 0; kc < 4; ++kc) {
#pragma unroll
        for (int tap = 0; tap < 9; ++tap) {
            int di = tap / 3, dj = tap % 3;
            s16x8 af[4];
#pragma unroll
            for (int mt = 0; mt < 4; ++mt)
                af[mt] = *(const s16x8*)(wA2 + ((((tap * 4 + kc) * 8 + wm * 4 + mt) * 64 + lane) << 3));
            int r = wn + di;
#pragma unroll
            for (int nt = 0; nt < 4; ++nt) {
                int jin = nt * 16 + (lane & 15) + dj;   // j_out + dj maps halo [0..65]
                s16x8 bf = *(const s16x8*)(&sB2[r][jin][kc * 32 + (lane >> 4) * 8]);
#pragma unroll
                for (int mt = 0; mt < 4; ++mt)
                    acc[mt][nt] = __builtin_amdgcn_mfma_f32_16x16x32_bf16(af[mt], bf, acc[mt][nt], 0, 0, 0);
            }
        }
    }

    // epilogue: m2r = lk(acc+bias) (fp32 out), fused scores
    int i = i0 + wn;
    float part[4] = {0.f, 0.f, 0.f, 0.f};
#pragma unroll
    for (int mt = 0; mt < 4; ++mt) {
        int o0 = wm * 64 + mt * 16 + (lane >> 4) * 4;
        float4 bb = *(const float4*)(b2 + o0);
        float4 sw = *(const float4*)(score_w + o0);
#pragma unroll
        for (int nt = 0; nt < 4; ++nt) {
            int j = nt * 16 + (lane & 15);
            f32x4 a = acc[mt][nt];
            float v0 = lk(a[0] + bb.x), v1 = lk(a[1] + bb.y);
            float v2 = lk(a[2] + bb.z), v3 = lk(a[3] + bb.w);
            float* dst = m2r + ((b * 128 + o0) * 64 + i) * 64 + j;
            dst[0] = v0; dst[4096] = v1; dst[8192] = v2; dst[12288] = v3;
            part[nt] += sw.x * v0 + sw.y * v1 + sw.z * v2 + sw.w * v3;
        }
    }
#pragma unroll
    for (int nt = 0; nt < 4; ++nt) {
        float p = part[nt];
        p += __shfl_xor(p, 16);
        p += __shfl_xor(p, 32);
        if ((lane & 48) == 0) sSc[wm][wn][nt * 16 + lane] = p;   // lanes 0..15
    }
    __syncthreads();
    if (t < 128) {
        int ii = t >> 6, j = t & 63;
        float s = sSc[0][ii][j] + sSc[1][ii][j];
        int gi = (b * 64 + i0 + ii) * 64 + j;
        g[gi] = gb[gi] + lk(s);
    }
}

// ---------------- K5: out_x / out_y: softmax(g) row/col, GEMV + residual
__global__ __launch_bounds__(128) void k_out(const float* __restrict__ g,
                                             const float* __restrict__ xl, const float* __restrict__ yl,
                                             const float* __restrict__ x, const float* __restrict__ y,
                                             float* __restrict__ out) {
    int blk = blockIdx.x;
    int which = blk >> 9; int r = blk & 511;
    int b = r >> 6, row = r & 63;
    int t = threadIdx.x;
    __shared__ float sW[64];
    if (t < 64) {
        float v = which ? g[(b * 64 + t) * 64 + row] : g[(b * 64 + row) * 64 + t];
        float mx = v;
        for (int off = 32; off > 0; off >>= 1) mx = fmaxf(mx, __shfl_xor(mx, off));
        float e = __expf(v - mx);
        float s = e;
        for (int off = 32; off > 0; off >>= 1) s += __shfl_xor(s, off);
        sW[t] = e / s;
    }
    __syncthreads();
    const float* lin = which ? xl : yl;
    const float* res = which ? y : x;
    float acc = 0.f;
#pragma unroll 4
    for (int k = 0; k < 64; ++k) acc += sW[k] * lin[(b * 64 + k) * NC + t];
    float ov = acc + res[(b * NC + t) * 64 + row];
    out[(which ? 65536 : 0) + (b * NC + t) * 64 + row] = ov;
}

extern "C" void kernel_launch(void* const* d_in, const int* in_sizes, int n_in,
                              void* d_out, int out_size, void* d_ws, size_t ws_size,
                              hipStream_t stream) {
    const float* x = (const float*)d_in[0];
    const float* y = (const float*)d_in[1];
    const float* m_bias = (const float*)d_in[2];
    const int* edge_mat = (const int*)d_in[3];
    const float* p_bias = (const float*)d_in[4];
    const int* path_mat = (const int*)d_in[5];
    const float* pre = (const float*)d_in[6];
    const float* xc1 = (const float*)d_in[7];
    const float* yc1 = (const float*)d_in[8];
    const float* xc2w = (const float*)d_in[9];
    const float* xc2b = (const float*)d_in[10];
    const float* yc2w = (const float*)d_in[11];
    const float* yc2b = (const float*)d_in[12];
    const float* pconv = (const float*)d_in[13];
    const float* econv = (const float*)d_in[14];
    const float* w1 = (const float*)d_in[15];
    const float* b1 = (const float*)d_in[16];
    const float* w2 = (const float*)d_in[17];
    const float* b2 = (const float*)d_in[18];
    const float* score_w = (const float*)d_in[19];
    const float* xlw = (const float*)d_in[20];
    const float* ylw = (const float*)d_in[21];
    const float* etab = (const float*)d_in[22];
    const float* ptab = (const float*)d_in[23];

    float* xf = (float*)d_ws;               // 65536 f
    float* yf = xf + 65536;
    float* xl = yf + 65536;
    float* yl = xl + 65536;
    float* Lw = yl + 65536;                 // 32768 f
    float* gb = Lw + 32768;
    float* g = gb + 32768;
    u16* wA1 = (u16*)(g + 32768);           // 49152 bf16
    u16* wA2 = wA1 + 49152;                 // 147456 bf16
    u16* xret = wA2 + 147456;               // 4194304 bf16
    u16* yret = xret + 4194304;             // 4194304 bf16
    u16* hT = yret + 4194304;               // 4194304 bf16  (~25.6 MiB total)

    float* out = (float*)d_out;
    float* out_m2r = out + 131072;

    hipLaunchKernelGGL(k_prepw, dim3(768), dim3(256), 0, stream, w1, w2, wA1, wA2);
    hipLaunchKernelGGL(k_feat, dim3(2048), dim3(64), 0, stream, x, y, xc1, yc1, xf, yf);
    hipLaunchKernelGGL(k_lin, dim3(1024), dim3(128), 0, stream, x, y, xlw, ylw, xl, yl);
    hipLaunchKernelGGL(k_selfother, dim3(8), dim3(64), 0, stream, xf, yf, xc2w, xc2b, yc2w, yc2b,
                       etab, econv, edge_mat, m_bias, Lw, gb);
    hipLaunchKernelGGL(k_attn, dim3(512), dim3(256), 0, stream, Lw, xf, yf, path_mat, p_bias,
                       ptab, pconv, xret, yret);
    hipLaunchKernelGGL(k_conv1, dim3(512), dim3(256), 0, stream, xret, yret, pre, wA1, b1, hT);
    hipLaunchKernelGGL(k_conv2, dim3(256), dim3(256), 0, stream, hT, wA2, b2, score_w, gb,
                       out_m2r, g);
    hipLaunchKernelGGL(k_out, dim3(1024), dim3(128), 0, stream, g, xl, yl, x, y, out);
}

// Round 4
// 213.703 us; speedup vs baseline: 2.3994x; 1.1827x over previous
//
#include <hip/hip_runtime.h>
#include <hip/hip_bf16.h>

// B=8, E=64, CIN=C=PRE=128, DME=DEN=32, edge types 10, path types 20.
// fp32 I/O; internal bf16 (xfb/yfb/menT/hT) + bf16 MFMA for attn GEMMs, conv1, conv2.

typedef unsigned short u16;
typedef unsigned int u32;
typedef short s16x8 __attribute__((ext_vector_type(8)));
typedef float f32x4 __attribute__((ext_vector_type(4)));

#define NB 8
#define NE 64
#define NC 128

__device__ __forceinline__ float b2f(u16 u) { return __uint_as_float(((u32)u) << 16); }
__device__ __forceinline__ u16 f2b(float f) {
    u32 x = __float_as_uint(f);
    u32 r = (x + 0x7fffu + ((x >> 16) & 1u)) >> 16;   // RNE
    return (u16)r;
}
__device__ __forceinline__ float lk(float v) { return v >= 0.f ? v : 0.1f * v; }

// ---------------- K0: weights -> bf16 MFMA A-fragment order (unchanged, validated R3)
__global__ __launch_bounds__(256) void k_prepw(const float* __restrict__ w1, const float* __restrict__ w2,
                                               u16* __restrict__ wA1, u16* __restrict__ wA2) {
    int idx = blockIdx.x * 256 + threadIdx.x;
    if (idx < 49152) {
        int e = idx & 7, lane = (idx >> 3) & 63, mtg = (idx >> 9) & 7, kc = idx >> 12;
        int o = mtg * 16 + (lane & 15), c = kc * 32 + ((lane >> 4) << 3) + e;
        wA1[idx] = f2b(w1[o * 384 + c]);
    } else {
        int id2 = idx - 49152;
        if (id2 < 147456) {
            int e = id2 & 7, lane = (id2 >> 3) & 63, mtg = (id2 >> 9) & 7;
            int kc = (id2 >> 12) & 3, tap = id2 >> 14;
            int o = mtg * 16 + (lane & 15), c = kc * 32 + ((lane >> 4) << 3) + e;
            wA2[id2] = f2b(w2[(o * 128 + c) * 9 + tap]);
        }
    }
}

// ---------------- K1: x_f[b,c,m] -> bf16 xfb/yfb [b][c][m]
__global__ __launch_bounds__(64) void k_feat(const float* __restrict__ x, const float* __restrict__ y,
                                             const float* __restrict__ xc1, const float* __restrict__ yc1,
                                             u16* __restrict__ xfb, u16* __restrict__ yfb) {
    int blk = blockIdx.x;
    int which = blk >> 10; int r = blk & 1023;
    int b = r >> 7, c = r & 127;
    const float* in = which ? y : x;
    const float* w = which ? yc1 : xc1;
    u16* out = which ? yfb : xfb;
    int m = threadIdx.x;
    const float* wr = w + c * NC;
    const float* ib = in + b * NC * NE + m;
    float acc = 0.f;
#pragma unroll 8
    for (int i = 0; i < NC; ++i) acc += wr[i] * ib[i * NE];
    out[(b * NC + c) * NE + m] = f2b(acc);
}

// ---------------- K1t: transpose xfb[b][c][m] -> xfT[b][m][c] fp32 (for residual/selfother)
__global__ __launch_bounds__(256) void k_transf(const u16* __restrict__ xfb, const u16* __restrict__ yfb,
                                                float* __restrict__ xfT, float* __restrict__ yfT) {
    int blk = blockIdx.x;
    int which = blk >> 3, b = blk & 7;
    const u16* src = which ? yfb : xfb;
    float* dst = which ? yfT : xfT;
    int t = threadIdx.x;
    int m = t >> 2, cq = t & 3;
    for (int o = 0; o < 8; ++o) {
        int c0 = cq * 32 + o * 4;
        float4 v;
        v.x = b2f(src[(b * 128 + c0 + 0) * 64 + m]);
        v.y = b2f(src[(b * 128 + c0 + 1) * 64 + m]);
        v.z = b2f(src[(b * 128 + c0 + 2) * 64 + m]);
        v.w = b2f(src[(b * 128 + c0 + 3) * 64 + m]);
        *(float4*)(dst + (b * 64 + m) * 128 + c0) = v;
    }
}

// ---------------- K1L: x_lin[b,m,i] (unchanged)
__global__ __launch_bounds__(128) void k_lin(const float* __restrict__ x, const float* __restrict__ y,
                                             const float* __restrict__ xlw, const float* __restrict__ ylw,
                                             float* __restrict__ xl, float* __restrict__ yl) {
    int blk = blockIdx.x;
    int which = blk >> 9; int r = blk & 511;
    int b = r >> 6, ent = r & 63;
    const float* in = which ? y : x;
    const float* w = which ? ylw : xlw;
    float* out = which ? yl : xl;
    int i = threadIdx.x;
    float acc = 0.f;
#pragma unroll 4
    for (int j = 0; j < NC; ++j) acc += w[i * NC + j] * in[(b * NC + j) * NE + ent];
    out[(b * NE + ent) * NC + i] = acc;
}

// ---------------- K1b: L = leaky(xs[j]+yo[i]), gbase; regridded 64 blocks
__global__ __launch_bounds__(64) void k_selfother(const float* __restrict__ xfT, const float* __restrict__ yfT,
                                                  const float* __restrict__ xc2w, const float* __restrict__ xc2b,
                                                  const float* __restrict__ yc2w, const float* __restrict__ yc2b,
                                                  const float* __restrict__ etab, const float* __restrict__ econv,
                                                  const int* __restrict__ edge_mat, const float* __restrict__ m_bias,
                                                  float* __restrict__ Lw, float* __restrict__ gb) {
    int b = blockIdx.x >> 3, ig = blockIdx.x & 7;
    int t = threadIdx.x;
    __shared__ float sXs[64], sYo[64], sEd[16];
    const float* xr = xfT + (b * 64 + t) * 128;
    const float* yr = yfT + (b * 64 + t) * 128;
    float ax = 0.f, ay = 0.f;
#pragma unroll 4
    for (int c = 0; c < NC; ++c) {
        ax += xc2w[c] * xr[c];
        ay += yc2w[c] * yr[c];
    }
    sXs[t] = ax + xc2b[0];
    sYo[t] = ay + yc2b[0];
    if (t < 10) {
        float s = 0.f;
        for (int d = 0; d < 32; ++d) s += etab[t * 32 + d] * econv[d];
        sEd[t] = lk(s);
    }
    __syncthreads();
    for (int ii = 0; ii < 8; ++ii) {
        int i = ig * 8 + ii;
        int idx = (b * NE + i) * NE + t;
        float L = lk(sXs[t] + sYo[i]);
        Lw[idx] = L;
        gb[idx] = L + sEd[edge_mat[idx]] + m_bias[idx];
    }
}

// ---------------- K2: per (b,e) attention, MFMA GEMMs -> menT[b][e][j][c3] (c3<256)
__global__ __launch_bounds__(256) void k_attn(const float* __restrict__ Lw,
                                              const u16* __restrict__ xfb, const u16* __restrict__ yfb,
                                              const float* __restrict__ xfT, const float* __restrict__ yfT,
                                              const int* __restrict__ path_mat, const float* __restrict__ p_bias,
                                              const float* __restrict__ ptab, const float* __restrict__ pconv,
                                              u16* __restrict__ menT) {
    int b = blockIdx.x >> 6, e = blockIdx.x & 63;
    int t = threadIdx.x;
    int lane = t & 63, w = t >> 6;
    __shared__ float sA[64][68];      // local scores, padded
    __shared__ u16 Abf[64][72];       // row-softmax A, [m][n], rinv baked
    __shared__ u16 E2bf[64][72];      // col-exp E2', [n][m], cinv baked
    __shared__ float sRed[256];
    __shared__ float sPdot[20];

    if (t < 20) {
        float s = 0.f;
        for (int d = 0; d < 32; ++d) s += ptab[t * 32 + d] * pconv[d];
        sPdot[t] = lk(s);
    }
    __syncthreads();

    // P1: local[m][n] = L + pdot[path] + p_bias
    {
        int m = t >> 2, n0 = (t & 3) * 16;
        int base = (((b * 64 + e) * 64 + m) * 64 + n0);
        const int4* pm4 = (const int4*)(path_mat + base);
        const float4* pb4 = (const float4*)(p_bias + base);
        const float4* L4 = (const float4*)(Lw + (b * 64 + m) * 64 + n0);
#pragma unroll
        for (int q = 0; q < 4; ++q) {
            int4 pm = pm4[q]; float4 pb = pb4[q]; float4 l = L4[q];
            float4 v;
            v.x = l.x + sPdot[pm.x] + pb.x;
            v.y = l.y + sPdot[pm.y] + pb.y;
            v.z = l.z + sPdot[pm.z] + pb.z;
            v.w = l.w + sPdot[pm.w] + pb.w;
            *(float4*)&sA[m][n0 + q * 4] = v;
        }
    }
    __syncthreads();

    // P2: stats — waves 0-1: rows (2 thr/row); waves 2-3: cols (2 thr/col)
    if (t < 128) {
        int r = t >> 1, h = t & 1;
        const float4* rp = (const float4*)&sA[r][h * 32];
        float mx = -1e30f;
#pragma unroll
        for (int k = 0; k < 8; ++k) {
            float4 v = rp[k];
            mx = fmaxf(mx, fmaxf(fmaxf(v.x, v.y), fmaxf(v.z, v.w)));
        }
        mx = fmaxf(mx, __shfl_xor(mx, 1));
        float s = 0.f;
#pragma unroll
        for (int k = 0; k < 8; ++k) {
            float4 v = rp[k];
            s += __expf(v.x - mx) + __expf(v.y - mx) + __expf(v.z - mx) + __expf(v.w - mx);
        }
        s += __shfl_xor(s, 1);
        if (h == 0) { sRed[r] = mx; sRed[64 + r] = 1.f / s; }
    } else {
        int n = (t - 128) >> 1, h = t & 1;
        float mx = -1e30f;
#pragma unroll
        for (int k = 0; k < 32; ++k) mx = fmaxf(mx, sA[h * 32 + k][n]);
        mx = fmaxf(mx, __shfl_xor(mx, 1));
        float s = 0.f;
#pragma unroll
        for (int k = 0; k < 32; ++k) s += __expf(sA[h * 32 + k][n] - mx);
        s += __shfl_xor(s, 1);
        if (h == 0) { sRed[128 + n] = mx; sRed[192 + n] = 1.f / s; }
    }
    __syncthreads();

    // P3a: A-pass (row-contiguous writes)
    {
        int m = t >> 2, q = t & 3;
        float rmax = sRed[m], rinv = sRed[64 + m];
        const float4* rp = (const float4*)&sA[m][q * 16];
        s16x8 pk[2];
#pragma unroll
        for (int g = 0; g < 2; ++g) {
            float4 v0 = rp[g * 2], v1 = rp[g * 2 + 1];
            pk[g][0] = (short)f2b(__expf(v0.x - rmax) * rinv);
            pk[g][1] = (short)f2b(__expf(v0.y - rmax) * rinv);
            pk[g][2] = (short)f2b(__expf(v0.z - rmax) * rinv);
            pk[g][3] = (short)f2b(__expf(v0.w - rmax) * rinv);
            pk[g][4] = (short)f2b(__expf(v1.x - rmax) * rinv);
            pk[g][5] = (short)f2b(__expf(v1.y - rmax) * rinv);
            pk[g][6] = (short)f2b(__expf(v1.z - rmax) * rinv);
            pk[g][7] = (short)f2b(__expf(v1.w - rmax) * rinv);
            *(s16x8*)&Abf[m][q * 16 + g * 8] = pk[g];
        }
    }
    // P3b: E2-pass (column threads -> row-contiguous writes of E2bf)
    {
        int n = t >> 2, q = t & 3;
        float cmax = sRed[128 + n], cinv = sRed[192 + n];
        s16x8 pk[2];
#pragma unroll
        for (int g = 0; g < 2; ++g) {
#pragma unroll
            for (int k = 0; k < 8; ++k) {
                float v = sA[q * 16 + g * 8 + k][n];
                pk[g][k] = (short)f2b(__expf(v - cmax) * cinv);
            }
            *(s16x8*)&E2bf[n][q * 16 + g * 8] = pk[g];
        }
    }
    __syncthreads();

    // P4: GEMM1: xret[c][m] = lk( sum_n A[m][n] yf[c][n] + xf[c][m] ), M=c N=m K=n
    int l15 = lane & 15, q4 = (lane >> 4);
    {
        f32x4 acc[2][4];
#pragma unroll
        for (int ci = 0; ci < 2; ++ci)
#pragma unroll
            for (int mt = 0; mt < 4; ++mt) acc[ci][mt] = (f32x4)(0.f);
#pragma unroll
        for (int kt = 0; kt < 2; ++kt) {
            s16x8 afr[2];
#pragma unroll
            for (int ci = 0; ci < 2; ++ci) {
                int c = (2 * w + ci) * 16 + l15;
                afr[ci] = *(const s16x8*)(yfb + (b * 128 + c) * 64 + kt * 32 + q4 * 8);
            }
            s16x8 bfr[4];
#pragma unroll
            for (int mt = 0; mt < 4; ++mt)
                bfr[mt] = *(const s16x8*)&Abf[mt * 16 + l15][kt * 32 + q4 * 8];
#pragma unroll
            for (int ci = 0; ci < 2; ++ci)
#pragma unroll
                for (int mt = 0; mt < 4; ++mt)
                    acc[ci][mt] = __builtin_amdgcn_mfma_f32_16x16x32_bf16(afr[ci], bfr[mt], acc[ci][mt], 0, 0, 0);
        }
#pragma unroll
        for (int ci = 0; ci < 2; ++ci) {
            int c0 = (2 * w + ci) * 16 + q4 * 4;
#pragma unroll
            for (int mt = 0; mt < 4; ++mt) {
                int m = mt * 16 + l15;
                float4 res = *(const float4*)(xfT + (b * 64 + m) * 128 + c0);
                f32x4 a = acc[ci][mt];
                u32 lo = (u32)f2b(lk(a[0] + res.x)) | ((u32)f2b(lk(a[1] + res.y)) << 16);
                u32 hi = (u32)f2b(lk(a[2] + res.z)) | ((u32)f2b(lk(a[3] + res.w)) << 16);
                *(uint2*)(menT + ((b * 64 + e) * 64 + m) * 384 + c0) = make_uint2(lo, hi);
            }
        }
    }
    // GEMM2: yret[c][n] = lk( sum_m E2'[n][m] xf[c][m] + yf[c][n] ), M=c N=n K=m
    {
        f32x4 acc[2][4];
#pragma unroll
        for (int ci = 0; ci < 2; ++ci)
#pragma unroll
            for (int nt = 0; nt < 4; ++nt) acc[ci][nt] = (f32x4)(0.f);
#pragma unroll
        for (int kt = 0; kt < 2; ++kt) {
            s16x8 afr[2];
#pragma unroll
            for (int ci = 0; ci < 2; ++ci) {
                int c = (2 * w + ci) * 16 + l15;
                afr[ci] = *(const s16x8*)(xfb + (b * 128 + c) * 64 + kt * 32 + q4 * 8);
            }
            s16x8 bfr[4];
#pragma unroll
            for (int nt = 0; nt < 4; ++nt)
                bfr[nt] = *(const s16x8*)&E2bf[nt * 16 + l15][kt * 32 + q4 * 8];
#pragma unroll
            for (int ci = 0; ci < 2; ++ci)
#pragma unroll
                for (int nt = 0; nt < 4; ++nt)
                    acc[ci][nt] = __builtin_amdgcn_mfma_f32_16x16x32_bf16(afr[ci], bfr[nt], acc[ci][nt], 0, 0, 0);
        }
#pragma unroll
        for (int ci = 0; ci < 2; ++ci) {
            int c0 = (2 * w + ci) * 16 + q4 * 4;
#pragma unroll
            for (int nt = 0; nt < 4; ++nt) {
                int n = nt * 16 + l15;
                float4 res = *(const float4*)(yfT + (b * 64 + n) * 128 + c0);
                f32x4 a = acc[ci][nt];
                u32 lo = (u32)f2b(lk(a[0] + res.x)) | ((u32)f2b(lk(a[1] + res.y)) << 16);
                u32 hi = (u32)f2b(lk(a[2] + res.z)) | ((u32)f2b(lk(a[3] + res.w)) << 16);
                *(uint2*)(menT + ((b * 64 + e) * 64 + n) * 384 + 128 + c0) = make_uint2(lo, hi);
            }
        }
    }
}

// ---------------- K2p: pre[b][p][i][j] fp32 -> menT[b][i][j][256+p] bf16
__global__ __launch_bounds__(256) void k_prepre(const float* __restrict__ pre, u16* __restrict__ menT) {
    int b = blockIdx.x >> 6, i = blockIdx.x & 63;
    int t = threadIdx.x;
    int j = t & 63, pg = t >> 6;
#pragma unroll
    for (int oc = 0; oc < 4; ++oc) {
        int p0 = pg * 32 + oc * 8;
        s16x8 v;
#pragma unroll
        for (int k = 0; k < 8; ++k)
            v[k] = (short)f2b(pre[((b * 128 + p0 + k) * 64 + i) * 64 + j]);
        *(s16x8*)(menT + ((b * 64 + i) * 64 + j) * 384 + 256 + p0) = v;
    }
}

// ---------------- K3: conv1 (1x1, 384->128) MFMA, zero LDS: A=wA1(global), B=menT(global)
__global__ __launch_bounds__(256) void k_conv1(const u16* __restrict__ menT, const u16* __restrict__ wA1,
                                               const float* __restrict__ b1, u16* __restrict__ hT) {
    int b = blockIdx.x >> 6, i = blockIdx.x & 63;
    int t = threadIdx.x;
    int lane = t & 63, w = t >> 6, wm = w & 1, wn = w >> 1;
    int l15 = lane & 15, q4 = lane >> 4;

    f32x4 acc[4][2];
#pragma unroll
    for (int mt = 0; mt < 4; ++mt)
#pragma unroll
        for (int nt = 0; nt < 2; ++nt) acc[mt][nt] = (f32x4)(0.f);

    const u16* mrow = menT + (b * 64 + i) * 64 * 384;
    for (int kc = 0; kc < 12; ++kc) {
        s16x8 af[4];
#pragma unroll
        for (int mt = 0; mt < 4; ++mt)
            af[mt] = *(const s16x8*)(wA1 + (((kc * 8 + wm * 4 + mt) * 64 + lane) << 3));
        s16x8 bf[2];
#pragma unroll
        for (int nt = 0; nt < 2; ++nt) {
            int j = (wn * 2 + nt) * 16 + l15;
            bf[nt] = *(const s16x8*)(mrow + j * 384 + kc * 32 + q4 * 8);
        }
#pragma unroll
        for (int mt = 0; mt < 4; ++mt)
#pragma unroll
            for (int nt = 0; nt < 2; ++nt)
                acc[mt][nt] = __builtin_amdgcn_mfma_f32_16x16x32_bf16(af[mt], bf[nt], acc[mt][nt], 0, 0, 0);
    }

#pragma unroll
    for (int mt = 0; mt < 4; ++mt) {
        int o0 = (wm * 4 + mt) * 16 + q4 * 4;
        float4 bb = *(const float4*)(b1 + o0);
#pragma unroll
        for (int nt = 0; nt < 2; ++nt) {
            int j = (wn * 2 + nt) * 16 + l15;
            f32x4 a = acc[mt][nt];
            u32 lo = (u32)f2b(lk(a[0] + bb.x)) | ((u32)f2b(lk(a[1] + bb.y)) << 16);
            u32 hi = (u32)f2b(lk(a[2] + bb.z)) | ((u32)f2b(lk(a[3] + bb.w)) << 16);
            *(uint2*)(hT + ((b * 64 + i) * 64 + j) * 128 + o0) = make_uint2(lo, hi);
        }
    }
}

// ---------------- K4: conv2 (3x3 SAME) MFMA + fused scores -> g (unchanged from R3)
__global__ __launch_bounds__(256) void k_conv2(const u16* __restrict__ hT, const u16* __restrict__ wA2,
                                               const float* __restrict__ b2, const float* __restrict__ score_w,
                                               const float* __restrict__ gb, float* __restrict__ m2r,
                                               float* __restrict__ g) {
    int b = blockIdx.x >> 5, ip = blockIdx.x & 31;
    int i0 = ip * 2;
    int t = threadIdx.x;
    int lane = t & 63, w = t >> 6, wm = w & 1, wn = w >> 1;
    __shared__ u16 sB2[4][66][136];
    __shared__ float sSc[2][2][64];

#pragma unroll
    for (int q = 0; q < 2; ++q) {
        int u = q * 256 + t;
        int r = u >> 7, hcol = (u >> 6) & 1, c2 = u & 63;
        *(u32*)&sB2[r][hcol ? 65 : 0][c2 * 2] = 0u;
    }
    for (int it = 0; it < 16; ++it) {
        int u = it * 256 + t;
        int cg = u & 15, j = (u >> 4) & 63, r = u >> 10;
        int ir = i0 - 1 + r;
        int4 v = make_int4(0, 0, 0, 0);
        if (ir >= 0 && ir < 64)
            v = *(const int4*)(hT + ((b * 64 + ir) * 64 + j) * 128 + cg * 8);
        *(int4*)&sB2[r][j + 1][cg * 8] = v;
    }
    __syncthreads();

    f32x4 acc[4][4];
#pragma unroll
    for (int mt = 0; mt < 4; ++mt)
#pragma unroll
        for (int nt = 0; nt < 4; ++nt) acc[mt][nt] = (f32x4)(0.f);

    for (int kc = 0; kc < 4; ++kc) {
#pragma unroll
        for (int tap = 0; tap < 9; ++tap) {
            int di = tap / 3, dj = tap % 3;
            s16x8 af[4];
#pragma unroll
            for (int mt = 0; mt < 4; ++mt)
                af[mt] = *(const s16x8*)(wA2 + ((((tap * 4 + kc) * 8 + wm * 4 + mt) * 64 + lane) << 3));
            int r = wn + di;
#pragma unroll
            for (int nt = 0; nt < 4; ++nt) {
                int jin = nt * 16 + (lane & 15) + dj;
                s16x8 bf = *(const s16x8*)(&sB2[r][jin][kc * 32 + (lane >> 4) * 8]);
#pragma unroll
                for (int mt = 0; mt < 4; ++mt)
                    acc[mt][nt] = __builtin_amdgcn_mfma_f32_16x16x32_bf16(af[mt], bf, acc[mt][nt], 0, 0, 0);
            }
        }
    }

    int i = i0 + wn;
    float part[4] = {0.f, 0.f, 0.f, 0.f};
#pragma unroll
    for (int mt = 0; mt < 4; ++mt) {
        int o0 = wm * 64 + mt * 16 + (lane >> 4) * 4;
        float4 bb = *(const float4*)(b2 + o0);
        float4 sw = *(const float4*)(score_w + o0);
#pragma unroll
        for (int nt = 0; nt < 4; ++nt) {
            int j = nt * 16 + (lane & 15);
            f32x4 a = acc[mt][nt];
            float v0 = lk(a[0] + bb.x), v1 = lk(a[1] + bb.y);
            float v2 = lk(a[2] + bb.z), v3 = lk(a[3] + bb.w);
            float* dst = m2r + ((b * 128 + o0) * 64 + i) * 64 + j;
            dst[0] = v0; dst[4096] = v1; dst[8192] = v2; dst[12288] = v3;
            part[nt] += sw.x * v0 + sw.y * v1 + sw.z * v2 + sw.w * v3;
        }
    }
#pragma unroll
    for (int nt = 0; nt < 4; ++nt) {
        float p = part[nt];
        p += __shfl_xor(p, 16);
        p += __shfl_xor(p, 32);
        if ((lane & 48) == 0) sSc[wm][wn][nt * 16 + lane] = p;
    }
    __syncthreads();
    if (t < 128) {
        int ii = t >> 6, j = t & 63;
        float s = sSc[0][ii][j] + sSc[1][ii][j];
        int gi = (b * 64 + i0 + ii) * 64 + j;
        g[gi] = gb[gi] + lk(s);
    }
}

// ---------------- K5: out_x / out_y (unchanged)
__global__ __launch_bounds__(128) void k_out(const float* __restrict__ g,
                                             const float* __restrict__ xl, const float* __restrict__ yl,
                                             const float* __restrict__ x, const float* __restrict__ y,
                                             float* __restrict__ out) {
    int blk = blockIdx.x;
    int which = blk >> 9; int r = blk & 511;
    int b = r >> 6, row = r & 63;
    int t = threadIdx.x;
    __shared__ float sW[64];
    if (t < 64) {
        float v = which ? g[(b * 64 + t) * 64 + row] : g[(b * 64 + row) * 64 + t];
        float mx = v;
        for (int off = 32; off > 0; off >>= 1) mx = fmaxf(mx, __shfl_xor(mx, off));
        float e = __expf(v - mx);
        float s = e;
        for (int off = 32; off > 0; off >>= 1) s += __shfl_xor(s, off);
        sW[t] = e / s;
    }
    __syncthreads();
    const float* lin = which ? xl : yl;
    const float* res = which ? y : x;
    float acc = 0.f;
#pragma unroll 4
    for (int k = 0; k < 64; ++k) acc += sW[k] * lin[(b * 64 + k) * NC + t];
    float ov = acc + res[(b * NC + t) * 64 + row];
    out[(which ? 65536 : 0) + (b * NC + t) * 64 + row] = ov;
}

extern "C" void kernel_launch(void* const* d_in, const int* in_sizes, int n_in,
                              void* d_out, int out_size, void* d_ws, size_t ws_size,
                              hipStream_t stream) {
    const float* x = (const float*)d_in[0];
    const float* y = (const float*)d_in[1];
    const float* m_bias = (const float*)d_in[2];
    const int* edge_mat = (const int*)d_in[3];
    const float* p_bias = (const float*)d_in[4];
    const int* path_mat = (const int*)d_in[5];
    const float* pre = (const float*)d_in[6];
    const float* xc1 = (const float*)d_in[7];
    const float* yc1 = (const float*)d_in[8];
    const float* xc2w = (const float*)d_in[9];
    const float* xc2b = (const float*)d_in[10];
    const float* yc2w = (const float*)d_in[11];
    const float* yc2b = (const float*)d_in[12];
    const float* pconv = (const float*)d_in[13];
    const float* econv = (const float*)d_in[14];
    const float* w1 = (const float*)d_in[15];
    const float* b1 = (const float*)d_in[16];
    const float* w2 = (const float*)d_in[17];
    const float* b2 = (const float*)d_in[18];
    const float* score_w = (const float*)d_in[19];
    const float* xlw = (const float*)d_in[20];
    const float* ylw = (const float*)d_in[21];
    const float* etab = (const float*)d_in[22];
    const float* ptab = (const float*)d_in[23];

    float* Lw = (float*)d_ws;               // 32768 f
    float* gb = Lw + 32768;                 // 32768 f
    float* g = gb + 32768;                  // 32768 f
    float* xfT = g + 32768;                 // 65536 f
    float* yfT = xfT + 65536;               // 65536 f
    float* xl = yfT + 65536;                // 65536 f
    float* yl = xl + 65536;                 // 65536 f
    u16* wA1 = (u16*)(yl + 65536);          // 49152 u16
    u16* wA2 = wA1 + 49152;                 // 147456 u16
    u16* xfb = wA2 + 147456;                // 65536 u16
    u16* yfb = xfb + 65536;                 // 65536 u16
    u16* menT = yfb + 65536;                // 12582912 u16 (24 MiB)
    u16* hT = menT + 12582912;              // 4194304 u16 (8 MiB)  total ~35.7 MiB

    float* out = (float*)d_out;
    float* out_m2r = out + 131072;

    hipLaunchKernelGGL(k_prepw, dim3(768), dim3(256), 0, stream, w1, w2, wA1, wA2);
    hipLaunchKernelGGL(k_feat, dim3(2048), dim3(64), 0, stream, x, y, xc1, yc1, xfb, yfb);
    hipLaunchKernelGGL(k_transf, dim3(16), dim3(256), 0, stream, xfb, yfb, xfT, yfT);
    hipLaunchKernelGGL(k_lin, dim3(1024), dim3(128), 0, stream, x, y, xlw, ylw, xl, yl);
    hipLaunchKernelGGL(k_selfother, dim3(64), dim3(64), 0, stream, xfT, yfT, xc2w, xc2b, yc2w, yc2b,
                       etab, econv, edge_mat, m_bias, Lw, gb);
    hipLaunchKernelGGL(k_attn, dim3(512), dim3(256), 0, stream, Lw, xfb, yfb, xfT, yfT,
                       path_mat, p_bias, ptab, pconv, menT);
    hipLaunchKernelGGL(k_prepre, dim3(512), dim3(256), 0, stream, pre, menT);
    hipLaunchKernelGGL(k_conv1, dim3(512), dim3(256), 0, stream, menT, wA1, b1, hT);
    hipLaunchKernelGGL(k_conv2, dim3(256), dim3(256), 0, stream, hT, wA2, b2, score_w, gb,
                       out_m2r, g);
    hipLaunchKernelGGL(k_out, dim3(1024), dim3(128), 0, stream, g, xl, yl, x, y, out);
}